// Round 6
// baseline (190.640 us; speedup 1.0000x reference)
//
#include <hip/hip_runtime.h>
#include <math.h>

#define NCAT  5
#define BATCH 64
#define ELEMS 196608          // C*H*W
#define P4    49152           // ELEMS/4 float4 positions
#define EPSV  1e-6f

// phased-path geometry
#define TILE4 512             // float4 positions per pos-tile (8 KB bytes)
#define NPOSB 96              // 96*512 = 49152
#define BCH   8               // batches per chunk
#define NCH   8               // 8 chunks * 8 batches = 64
#define NCOLS (NPOSB * NCH)   // 768 partial columns

// legacy fallback geometry
#define NBLK 768
#define TPB  256
#define GRP  8

__device__ __forceinline__ float hsum4(const float4 v) {
    return v.x + v.y + v.z + v.w;
}
__device__ __forceinline__ float dot4(const float4 a, const float4 b) {
    return a.x * b.x + a.y * b.y + a.z * b.z + a.w * b.w;
}

// ---------------- Phase 1: un pass (8 KB contiguous runs) -------------------
// grid (NPOSB, NCH). Reads un; writes unpart[NCH][NCAT][P4] float4 partial
// maps and unblk[NCAT][NCOLS] block sums (for the bn term).
__global__ __launch_bounds__(256) void un_pass_kernel(
    const float4* __restrict__ un,
    const int*    __restrict__ de_id,
    float4*       __restrict__ unpart,
    float*        __restrict__ unblk)
{
    __shared__ int   sh_de[BCH];
    __shared__ float sred[4][NCAT];

    const int tid = threadIdx.x;
    const int pb  = blockIdx.x;      // pos tile
    const int ch  = blockIdx.y;      // batch chunk
    if (tid < BCH) sh_de[tid] = de_id[ch * BCH + tid];
    __syncthreads();

    const int p0 = pb * TILE4 + tid;             // slot s position: p0 + s*256
    const float4* up = un + p0;

    float4 un_s[2][NCAT];
    #pragma unroll
    for (int s = 0; s < 2; ++s)
        #pragma unroll
        for (int j = 0; j < NCAT; ++j)
            un_s[s][j] = make_float4(0.f, 0.f, 0.f, 0.f);

    float4 ub[2][2];
    #pragma unroll
    for (int s = 0; s < 2; ++s)
        ub[0][s] = up[(size_t)(ch * BCH) * P4 + (s << 8)];

    #pragma unroll
    for (int b = 0; b < BCH; ++b) {
        const int cur = b & 1, nxt = cur ^ 1;
        if (b < BCH - 1) {
            #pragma unroll
            for (int s = 0; s < 2; ++s)
                ub[nxt][s] = up[(size_t)(ch * BCH + b + 1) * P4 + (s << 8)];
        }
        const int k = sh_de[b];
        #pragma unroll
        for (int j = 0; j < NCAT; ++j) {
            const float m = (k == j) ? 1.0f : 0.0f;
            #pragma unroll
            for (int s = 0; s < 2; ++s) {
                un_s[s][j].x = fmaf(m, ub[cur][s].x, un_s[s][j].x);
                un_s[s][j].y = fmaf(m, ub[cur][s].y, un_s[s][j].y);
                un_s[s][j].z = fmaf(m, ub[cur][s].z, un_s[s][j].z);
                un_s[s][j].w = fmaf(m, ub[cur][s].w, un_s[s][j].w);
            }
        }
    }

    // store partial maps (coalesced)
    #pragma unroll
    for (int j = 0; j < NCAT; ++j)
        #pragma unroll
        for (int s = 0; s < 2; ++s)
            unpart[(size_t)(ch * NCAT + j) * P4 + p0 + (s << 8)] = un_s[s][j];

    // per-block un sums (bn term)
    float vals[NCAT];
    #pragma unroll
    for (int j = 0; j < NCAT; ++j)
        vals[j] = hsum4(un_s[0][j]) + hsum4(un_s[1][j]);

    #pragma unroll
    for (int j = 0; j < NCAT; ++j) {
        float v = vals[j];
        #pragma unroll
        for (int off = 32; off >= 1; off >>= 1)
            v += __shfl_down(v, off, 64);
        vals[j] = v;
    }
    const int wave = tid >> 6, lane = tid & 63;
    if (lane == 0) {
        #pragma unroll
        for (int j = 0; j < NCAT; ++j) sred[wave][j] = vals[j];
    }
    __syncthreads();
    if (tid < NCAT) {
        float v = sred[0][tid] + sred[1][tid] + sred[2][tid] + sred[3][tid];
        unblk[tid * NCOLS + ch * NPOSB + pb] = v;
    }
}

// ---------------- Phase 1b: combine partials -> reciprocal map ---------------
// grid (P4/256, NCAT). All traffic is L3-resident.
__global__ __launch_bounds__(256) void rmap_kernel(
    const int*    __restrict__ de_id,
    const float4* __restrict__ unpart,
    float4*       __restrict__ rmap)
{
    __shared__ float sh_inv[NCAT];
    const int tid = threadIdx.x;
    if (tid < 64) {
        int k = de_id[tid];
        #pragma unroll
        for (int j = 0; j < NCAT; ++j) {
            unsigned long long m = __ballot(k == j);
            if (tid == j) {
                int c = __popcll(m);
                sh_inv[j] = 1.0f / (float)(c > 0 ? c : 1);
            }
        }
    }
    __syncthreads();

    const int p4  = blockIdx.x * 256 + tid;
    const int cat = blockIdx.y;

    float4 s = make_float4(0.f, 0.f, 0.f, 0.f);
    #pragma unroll
    for (int ch = 0; ch < NCH; ++ch) {
        float4 v = unpart[(size_t)(ch * NCAT + cat) * P4 + p4];
        s.x += v.x; s.y += v.y; s.z += v.z; s.w += v.w;
    }
    const float inv = sh_inv[cat];
    float4 r;
    r.x = 1.0f / fmaf(s.x, inv, EPSV);
    r.y = 1.0f / fmaf(s.y, inv, EPSV);
    r.z = 1.0f / fmaf(s.z, inv, EPSV);
    r.w = 1.0f / fmaf(s.w, inv, EPSV);
    rmap[(size_t)cat * P4 + p4] = r;
}

// ---------------- Phase 2: abs-diff pass (8 KB contiguous runs) --------------
// grid (NPOSB, NCH). Reads restored+clean + rmap; writes part2[10][NCOLS]:
// rows 0..4 scaled sums, 5..9 abs sums.
__global__ __launch_bounds__(256) void ad_pass_kernel(
    const float4* __restrict__ restored,
    const float4* __restrict__ clean,
    const float4* __restrict__ rmap,
    const int*    __restrict__ de_id,
    float*        __restrict__ part2)
{
    __shared__ int   sh_de[BCH];
    __shared__ float sred[4][2 * NCAT];

    const int tid = threadIdx.x;
    const int pb  = blockIdx.x;
    const int ch  = blockIdx.y;
    if (tid < BCH) sh_de[tid] = de_id[ch * BCH + tid];
    __syncthreads();

    const int p0 = pb * TILE4 + tid;
    const float4* cp = clean + p0;
    const float4* rp = restored + p0;

    float4 ad_s[2][NCAT];
    #pragma unroll
    for (int s = 0; s < 2; ++s)
        #pragma unroll
        for (int j = 0; j < NCAT; ++j)
            ad_s[s][j] = make_float4(0.f, 0.f, 0.f, 0.f);

    float4 cb[2][2], rb[2][2];
    #pragma unroll
    for (int s = 0; s < 2; ++s) {
        const size_t off = (size_t)(ch * BCH) * P4 + (s << 8);
        cb[0][s] = cp[off];
        rb[0][s] = rp[off];
    }

    #pragma unroll
    for (int b = 0; b < BCH; ++b) {
        const int cur = b & 1, nxt = cur ^ 1;
        if (b < BCH - 1) {
            #pragma unroll
            for (int s = 0; s < 2; ++s) {
                const size_t off = (size_t)(ch * BCH + b + 1) * P4 + (s << 8);
                cb[nxt][s] = cp[off];
                rb[nxt][s] = rp[off];
            }
        }
        const int k = sh_de[b];
        #pragma unroll
        for (int s = 0; s < 2; ++s) {
            float ax = fabsf(cb[cur][s].x - rb[cur][s].x);
            float ay = fabsf(cb[cur][s].y - rb[cur][s].y);
            float az = fabsf(cb[cur][s].z - rb[cur][s].z);
            float aw = fabsf(cb[cur][s].w - rb[cur][s].w);
            #pragma unroll
            for (int j = 0; j < NCAT; ++j) {
                const float m = (k == j) ? 1.0f : 0.0f;
                ad_s[s][j].x = fmaf(m, ax, ad_s[s][j].x);
                ad_s[s][j].y = fmaf(m, ay, ad_s[s][j].y);
                ad_s[s][j].z = fmaf(m, az, ad_s[s][j].z);
                ad_s[s][j].w = fmaf(m, aw, ad_s[s][j].w);
            }
        }
    }

    float vals[2 * NCAT];
    #pragma unroll
    for (int j = 0; j < NCAT; ++j) {
        float4 m0 = rmap[(size_t)j * P4 + p0];
        float4 m1 = rmap[(size_t)j * P4 + p0 + 256];
        vals[j]        = dot4(ad_s[0][j], m0) + dot4(ad_s[1][j], m1);
        vals[NCAT + j] = hsum4(ad_s[0][j]) + hsum4(ad_s[1][j]);
    }

    #pragma unroll
    for (int i = 0; i < 2 * NCAT; ++i) {
        float v = vals[i];
        #pragma unroll
        for (int off = 32; off >= 1; off >>= 1)
            v += __shfl_down(v, off, 64);
        vals[i] = v;
    }
    const int wave = tid >> 6, lane = tid & 63;
    if (lane == 0) {
        #pragma unroll
        for (int i = 0; i < 2 * NCAT; ++i) sred[wave][i] = vals[i];
    }
    __syncthreads();
    if (tid < 2 * NCAT) {
        float v = sred[0][tid] + sred[1][tid] + sred[2][tid] + sred[3][tid];
        part2[tid * NCOLS + ch * NPOSB + pb] = v;
    }
}

// ---------------- Legacy single-pass (ws fallback; R3 structure) -------------
__global__ __launch_bounds__(TPB) void accum_kernel(
    const float* __restrict__ restored,
    const float* __restrict__ clean,
    const int*   __restrict__ de_id,
    const float* __restrict__ un,
    float*       __restrict__ partials)
{
    __shared__ int   sh_de[BATCH];
    __shared__ float sh_inv[NCAT];
    __shared__ float sred[TPB / 64][3 * NCAT];

    const int tid = threadIdx.x;
    if (tid < 64) {
        int k = de_id[tid];
        sh_de[tid] = k;
        #pragma unroll
        for (int j = 0; j < NCAT; ++j) {
            unsigned long long m = __ballot(k == j);
            if (tid == j) {
                int c = __popcll(m);
                sh_inv[j] = 1.0f / (float)(c > 0 ? c : 1);
            }
        }
    }
    __syncthreads();

    const int p = blockIdx.x * TPB + tid;
    const float* rp = restored + p;
    const float* cp = clean + p;
    const float* up = un + p;

    float un_s[NCAT] = {0.f, 0.f, 0.f, 0.f, 0.f};
    float ad_s[NCAT] = {0.f, 0.f, 0.f, 0.f, 0.f};

    float ub[2][GRP], cb[2][GRP], rb[2][GRP];
    #pragma unroll
    for (int i = 0; i < GRP; ++i) {
        const size_t off = (size_t)i * ELEMS;
        ub[0][i] = up[off]; cb[0][i] = cp[off]; rb[0][i] = rp[off];
    }
    #pragma unroll
    for (int g = 0; g < BATCH / GRP; ++g) {
        const int cur = g & 1, nxt = cur ^ 1;
        if (g < BATCH / GRP - 1) {
            #pragma unroll
            for (int i = 0; i < GRP; ++i) {
                const size_t off = (size_t)((g + 1) * GRP + i) * ELEMS;
                ub[nxt][i] = up[off]; cb[nxt][i] = cp[off]; rb[nxt][i] = rp[off];
            }
        }
        #pragma unroll
        for (int i = 0; i < GRP; ++i) {
            float u  = ub[cur][i];
            float ad = fabsf(cb[cur][i] - rb[cur][i]);
            int   k  = sh_de[g * GRP + i];
            #pragma unroll
            for (int j = 0; j < NCAT; ++j) {
                float m = (k == j) ? 1.0f : 0.0f;
                un_s[j] = fmaf(m, u,  un_s[j]);
                ad_s[j] = fmaf(m, ad, ad_s[j]);
            }
        }
    }

    float vals[3 * NCAT];
    #pragma unroll
    for (int j = 0; j < NCAT; ++j) {
        float um = fmaf(un_s[j], sh_inv[j], EPSV);
        vals[j]            = ad_s[j] / um;
        vals[NCAT + j]     = ad_s[j];
        vals[2 * NCAT + j] = un_s[j];
    }
    #pragma unroll
    for (int i = 0; i < 3 * NCAT; ++i) {
        float v = vals[i];
        #pragma unroll
        for (int off = 32; off >= 1; off >>= 1)
            v += __shfl_down(v, off, 64);
        vals[i] = v;
    }
    const int wave = tid >> 6, lane = tid & 63;
    if (lane == 0) {
        #pragma unroll
        for (int i = 0; i < 3 * NCAT; ++i) sred[wave][i] = vals[i];
    }
    __syncthreads();
    if (tid < 3 * NCAT) {
        float v = sred[0][tid] + sred[1][tid] + sred[2][tid] + sred[3][tid];
        partials[tid * NBLK + blockIdx.x] = v;
    }
}

// ---------------- Epilogue ---------------------------------------------------
// rows 0..4 scaled, 5..9 abs from pSA[10][nA]; rows 10..14 un from pUN[5][nB].
__global__ __launch_bounds__(256) void epilogue_kernel(
    const int*   __restrict__ de_id,
    const float* __restrict__ pSA, int nA,
    const float* __restrict__ pUN, int nB,
    float*       __restrict__ out)
{
    __shared__ int   sh_cnt[NCAT];
    __shared__ float sh_acc[3 * NCAT];

    const int tid = threadIdx.x;
    if (tid < 64) {
        int k = de_id[tid];
        #pragma unroll
        for (int j = 0; j < NCAT; ++j) {
            unsigned long long m = __ballot(k == j);
            if (tid == j) sh_cnt[j] = __popcll(m);
        }
    }

    if (tid < 240) {
        const int row    = tid >> 4;
        const int lane16 = tid & 15;
        const float* base = (row < 10) ? (pSA + row * nA) : (pUN + (row - 10) * nB);
        const int n = (row < 10) ? nA : nB;
        float v = 0.f;
        for (int k = lane16; k < n; k += 16) v += base[k];
        v += __shfl_down(v, 8, 16);
        v += __shfl_down(v, 4, 16);
        v += __shfl_down(v, 2, 16);
        v += __shfl_down(v, 1, 16);
        if (lane16 == 0) sh_acc[row] = v;
    }
    __syncthreads();

    if (tid == 0) {
        const float Ef = (float)ELEMS;
        float cum_s = 0.f;
        long  cum_c = 0;
        float total = 0.f;
        int   num   = 0;
        float cat_losses[NCAT], old_loss[NCAT], bn[NCAT], unc_l1[NCAT];

        for (int j = 0; j < NCAT; ++j) {
            cum_s += sh_acc[j];
            cum_c += sh_cnt[j];
            float cum_elems = (float)cum_c * Ef;
            float cum_l1    = cum_s / fmaxf(cum_elems, 1.0f);

            bool  ne   = sh_cnt[j] > 0;
            float safe = (float)(ne ? sh_cnt[j] : 1);

            old_loss[j]  = ne ? sh_acc[NCAT + j] / (safe * Ef) : 0.f;
            float un_num = sh_acc[2 * NCAT + j] / (safe * Ef) + EPSV;
            bn[j]        = ne ? 2.0f * logf(un_num) : 0.f;
            unc_l1[j]    = ne ? cum_l1 : 0.f;
            cat_losses[j] = unc_l1[j] + bn[j];
            total += cat_losses[j];
            num   += ne ? 1 : 0;
        }
        total /= (float)num;

        out[0] = total;
        for (int j = 0; j < NCAT; ++j) {
            out[1 + j]  = cat_losses[j];
            out[6 + j]  = old_loss[j];
            out[11 + j] = bn[j];
            out[16 + j] = unc_l1[j];
        }
    }
}

extern "C" void kernel_launch(void* const* d_in, const int* in_sizes, int n_in,
                              void* d_out, int out_size, void* d_ws, size_t ws_size,
                              hipStream_t stream) {
    (void)in_sizes; (void)n_in; (void)out_size;
    const float* restored = (const float*)d_in[0];
    const float* clean    = (const float*)d_in[1];
    const int*   de_id    = (const int*)d_in[2];
    const float* un       = (const float*)d_in[3];
    float* out = (float*)d_out;

    // ws layout: unpart[NCH][NCAT][P4] float4 | rmap[NCAT][P4] float4 |
    //            unblk[NCAT][NCOLS] f32 | part2[10][NCOLS] f32
    const size_t unpart_b = (size_t)NCH * NCAT * P4 * sizeof(float4);
    const size_t rmap_b   = (size_t)NCAT * P4 * sizeof(float4);
    const size_t unblk_b  = (size_t)NCAT * NCOLS * sizeof(float);
    const size_t part2_b  = (size_t)10 * NCOLS * sizeof(float);

    if (ws_size >= unpart_b + rmap_b + unblk_b + part2_b) {
        float4* unpart = (float4*)d_ws;
        float4* rmap   = (float4*)((char*)d_ws + unpart_b);
        float*  unblk  = (float*)((char*)d_ws + unpart_b + rmap_b);
        float*  part2  = (float*)((char*)d_ws + unpart_b + rmap_b + unblk_b);

        un_pass_kernel<<<dim3(NPOSB, NCH), 256, 0, stream>>>(
            (const float4*)un, de_id, unpart, unblk);
        rmap_kernel<<<dim3(P4 / 256, NCAT), 256, 0, stream>>>(
            de_id, unpart, rmap);
        ad_pass_kernel<<<dim3(NPOSB, NCH), 256, 0, stream>>>(
            (const float4*)restored, (const float4*)clean, rmap, de_id, part2);
        epilogue_kernel<<<1, 256, 0, stream>>>(
            de_id, part2, NCOLS, unblk, NCOLS, out);
    } else {
        float* partials = (float*)d_ws;   // [15][NBLK]
        accum_kernel<<<NBLK, TPB, 0, stream>>>(restored, clean, de_id, un, partials);
        epilogue_kernel<<<1, 256, 0, stream>>>(
            de_id, partials, NBLK, partials + 10 * NBLK, NBLK, out);
    }
}